// Round 1
// baseline (114.851 us; speedup 1.0000x reference)
//
#include <hip/hip_runtime.h>

// ReconstructPatchImage: out[b,c,y,x] = sum of 8 permuted gathers of [B,HW,C] inputs.
// B=64, HW=196 (H=W=14), C=1024, all float32.
//
// Derived per-input flat (per-batch) source index for output (c, q=y*14+x):
//   in0 (l2r):  q*1024 + c
//   in1 (r2l):  (195-q)*1024 + c
//   in2 (t2b):  x*14336 + c*14 + y              (channel-mixing col-major view)
//   in3 (b2t):  (195 - x*14 - hi)*1024 + lo,  t=c*14+y, hi=t>>10, lo=t&1023
//   in4 (tl-br): p5[q]*1024 + c   (diag-order rank LUT)
//   in5 (br-tl): p6[q]*1024 + c   (reversed-diag rank LUT)
//   in6 (tr-bl): p7[q]*1024 + c   (antidiag rank LUT)
//   in7 (bl-tr): p7[195-q]*1024 + c

#define N_HW 196
#define N_C  1024

struct Luts { unsigned short p5[196], p6[196], p7[196]; };

constexpr Luts make_luts() {
    Luts L{};
    // diag order (top-left -> bottom-right), and antidiag (column-mirrored)
    int k = 0;
    for (int s = 0; s < 27; ++s) {
        int y0 = (s - 13 > 0) ? s - 13 : 0;
        int y1 = (s < 13) ? s : 13;
        for (int y = y0; y <= y1; ++y) {
            int x = s - y;
            L.p5[y * 14 + x] = (unsigned short)k;
            L.p7[y * 14 + (13 - x)] = (unsigned short)k;
            ++k;
        }
    }
    // diag_idx_rev: build forward (x descending per diagonal), then list-reverse.
    int k2 = 0;
    for (int s = 0; s < 27; ++s) {
        int x1 = (s < 13) ? s : 13;
        int x0 = (s - 13 > 0) ? s - 13 : 0;
        for (int x = x1; x >= x0; --x) {
            int y = s - x;
            L.p6[y * 14 + x] = (unsigned short)(195 - k2);
            ++k2;
        }
    }
    return L;
}

__constant__ Luts d_luts = make_luts();

__device__ __forceinline__ void gll16(const float* g, float* l) {
    __builtin_amdgcn_global_load_lds(
        (const __attribute__((address_space(1))) unsigned int*)g,
        (__attribute__((address_space(3))) unsigned int*)l,
        16, 0, 0);
}

__global__ __launch_bounds__(256) void recon_kernel(
    const float* __restrict__ in0, const float* __restrict__ in1,
    const float* __restrict__ in2, const float* __restrict__ in3,
    const float* __restrict__ in4, const float* __restrict__ in5,
    const float* __restrict__ in6, const float* __restrict__ in7,
    float* __restrict__ out)
{
    __shared__ __align__(16) float lds[12740];   // max(196*64, 196*65) floats
    const int tid  = threadIdx.x;
    const int lane = tid & 63;
    const int wv   = tid >> 6;
    const int w0   = __builtin_amdgcn_readfirstlane(wv);  // scalar wave id
    const int c0   = blockIdx.x * 64;                     // channel tile base
    const int b    = blockIdx.y;
    const size_t boff = (size_t)b * (N_HW * N_C);

    float acc[49];
    #pragma unroll
    for (int k = 0; k < 49; ++k) acc[k] = 0.f;

    // ---- staging: 49 chunks of 1 KiB (wave-wide width-16 global_load_lds) ----
    auto stage_perm = [&](const float* gb) {           // slab[p][cc] = gb[p*1024 + c0 + cc]
        for (int ch = wv; ch < 49; ch += 4) {
            int i  = ch * 64 + lane;
            int p  = i >> 4;
            int rf = (i & 15) << 2;
            gll16(gb + p * 1024 + c0 + rf, lds + ch * 256);
        }
    };
    auto stage_cm_fwd = [&](const float* gb) {         // slab[x][jj] = gb[x*14336 + c0*14 + jj]
        for (int ch = wv; ch < 49; ch += 4) {
            int i = ch * 64 + lane;
            int x = i / 224;
            int r = i - x * 224;                       // 16-byte group within segment
            gll16(gb + x * 14336 + c0 * 14 + r * 4, lds + ch * 256);
        }
    };
    auto stage_cm_rev = [&](const float* gb) {         // slab[x][jj] = gb[(195-x*14-hi)*1024 + lo]
        for (int ch = wv; ch < 49; ch += 4) {
            int i  = ch * 64 + lane;
            int x  = i / 224;
            int jj = (i - x * 224) << 2;
            int t  = c0 * 14 + jj;                     // groups never straddle t%1024==0
            int hi = t >> 10, lo = t & 1023;
            int p  = 195 - x * 14 - hi;
            gll16(gb + p * 1024 + lo, lds + ch * 256);
        }
    };

    // ---- accumulate: lane = channel, q = w0 + 4k (wave-uniform) ----
    auto acc_perm = [&](auto pf) {
        #pragma unroll
        for (int k = 0; k < 49; ++k) {
            int q = w0 + 4 * k;
            int p = pf(q);
            acc[k] += lds[p * 64 + lane];              // uniform row, lanes span 64 cols: conflict-free
        }
    };
    auto acc_cm = [&]() {
        #pragma unroll
        for (int k = 0; k < 49; ++k) {
            int q = w0 + 4 * k;
            int y = q / 14;
            int x = q - y * 14;
            acc[k] += lds[x * 896 + lane * 14 + y];    // stride-14 lanes: benign 4-way
        }
    };

    stage_perm(in0 + boff);  __syncthreads();
    acc_perm([](int q){ return q; });                  __syncthreads();

    stage_perm(in1 + boff);  __syncthreads();
    acc_perm([](int q){ return 195 - q; });            __syncthreads();

    stage_cm_fwd(in2 + boff); __syncthreads();
    acc_cm();                                          __syncthreads();

    stage_cm_rev(in3 + boff); __syncthreads();
    acc_cm();                                          __syncthreads();

    stage_perm(in4 + boff);  __syncthreads();
    acc_perm([](int q){ return (int)d_luts.p5[q]; });  __syncthreads();

    stage_perm(in5 + boff);  __syncthreads();
    acc_perm([](int q){ return (int)d_luts.p6[q]; });  __syncthreads();

    stage_perm(in6 + boff);  __syncthreads();
    acc_perm([](int q){ return (int)d_luts.p7[q]; });  __syncthreads();

    stage_perm(in7 + boff);  __syncthreads();
    acc_perm([](int q){ return (int)d_luts.p7[195 - q]; });
    __syncthreads();

    // ---- transpose via LDS (stride 65: conflict-free both sides), coalesced store ----
    #pragma unroll
    for (int k = 0; k < 49; ++k) {
        int q = w0 + 4 * k;
        lds[q * 65 + lane] = acc[k];
    }
    __syncthreads();
    float* ob = out + boff;
    for (int i = tid; i < 64 * 196; i += 256) {
        int cg = i / 196;
        int q  = i - cg * 196;
        ob[(c0 + cg) * 196 + q] = lds[q * 65 + cg];
    }
}

extern "C" void kernel_launch(void* const* d_in, const int* in_sizes, int n_in,
                              void* d_out, int out_size, void* d_ws, size_t ws_size,
                              hipStream_t stream) {
    dim3 grid(16, 64);   // x: channel tile (1024/64), y: batch
    dim3 block(256);
    recon_kernel<<<grid, block, 0, stream>>>(
        (const float*)d_in[0], (const float*)d_in[1], (const float*)d_in[2],
        (const float*)d_in[3], (const float*)d_in[4], (const float*)d_in[5],
        (const float*)d_in[6], (const float*)d_in[7], (float*)d_out);
}